// Round 5
// baseline (280.293 us; speedup 1.0000x reference)
//
#include <hip/hip_runtime.h>
#include <hip/hip_bf16.h>
#include <math.h>

#define N_NODES 50000
#define N_EDGES 800000
#define NEG_SLOPE 0.2f
#define EPS_DEN 1e-9f
#define MAXE_BLK 256

constexpr int SCAN_BLK = 1024;
constexpr int NB_SCAN = (N_NODES + SCAN_BLK - 1) / SCAN_BLK; // 49

__device__ inline unsigned short f2bf(float x) {
    __hip_bfloat16 h = __float2bfloat16(x);
    return *(unsigned short*)&h;
}
__device__ inline float bflo(unsigned int u) { return __uint_as_float(u << 16); }
__device__ inline float bfhi(unsigned int u) { return __uint_as_float(u & 0xffff0000u); }

// ---------------- CSR build ----------------

__global__ void count_k(const int* __restrict__ dst, int* __restrict__ deg) {
    int e = blockIdx.x * 256 + threadIdx.x;
    if (e < N_EDGES) atomicAdd(&deg[dst[e]], 1);
}

__global__ void scan1_k(const int* __restrict__ deg, int* __restrict__ off,
                        int* __restrict__ bsum) {
    __shared__ int sh[256];
    int b = blockIdx.x, t = threadIdx.x;
    int base = b * SCAN_BLK + t * 4;
    int v[4]; int s = 0;
    #pragma unroll
    for (int i = 0; i < 4; ++i) {
        int idx = base + i;
        v[i] = (idx < N_NODES) ? deg[idx] : 0;
        s += v[i];
    }
    sh[t] = s; __syncthreads();
    for (int ofs = 1; ofs < 256; ofs <<= 1) {
        int x = 0;
        if (t >= ofs) x = sh[t - ofs];
        __syncthreads();
        sh[t] += x;
        __syncthreads();
    }
    int excl = sh[t] - s;
    if (t == 255) bsum[b] = sh[255];
    int run = excl;
    #pragma unroll
    for (int i = 0; i < 4; ++i) {
        int idx = base + i;
        if (idx < N_NODES) off[idx] = run;
        run += v[i];
    }
}

// merged scan2+scan3
__global__ void scan3_k(int* __restrict__ off, const int* __restrict__ bsum) {
    __shared__ int pre;
    int b = blockIdx.x;
    if (threadIdx.x == 0) {
        int s = 0;
        int nb = b >> 2;
        for (int j = 0; j < nb; ++j) s += bsum[j];
        pre = s;
    }
    __syncthreads();
    int i = b * 256 + threadIdx.x;
    if (i < N_NODES) off[i] += pre;
    if (i == 0) off[N_NODES] = N_EDGES;
}

// scatter + layer-1 edge weights
__global__ void scatter_k(const int* __restrict__ src, const int* __restrict__ dst,
                          int* __restrict__ cursor, int* __restrict__ csr,
                          int* __restrict__ perm,
                          const float* __restrict__ el1, const float* __restrict__ er1,
                          float* __restrict__ wb1) {
    int e = blockIdx.x * 256 + threadIdx.x;
    if (e >= N_EDGES) return;
    int s = src[e], d = dst[e];
    int p = atomicAdd(&cursor[d], 1);
    csr[p] = s;
    perm[e] = p;
    float4 a = *(const float4*)&el1[(size_t)s * 4];
    float4 b = *(const float4*)&er1[(size_t)d * 4];
    float4 x = make_float4(a.x + b.x, a.y + b.y, a.z + b.z, a.w + b.w);
    x.x = x.x > 0.f ? x.x : NEG_SLOPE * x.x;
    x.y = x.y > 0.f ? x.y : NEG_SLOPE * x.y;
    x.z = x.z > 0.f ? x.z : NEG_SLOPE * x.z;
    x.w = x.w > 0.f ? x.w : NEG_SLOPE * x.w;
    float4 w = make_float4(__expf(x.x), __expf(x.y), __expf(x.z), __expf(x.w));
    *(float4*)&wb1[(size_t)p * 4] = w;
}

// ---------------- GEMM1 + fused el1/er1 + bf16 feat1 out ----------------
// 128x128 tile / 256 threads, 8x8 microtile. t = ty*16+tx.
// cols per thread: {tx*4..+3} U {64+tx*4..+3}; rows: ty*8..+7.

__global__ __launch_bounds__(256) void gemm1_k(const float* __restrict__ H,
                                               const float* __restrict__ W,
                                               const float* __restrict__ AL,
                                               const float* __restrict__ AR,
                                               unsigned short* __restrict__ Fb,
                                               float* __restrict__ el,
                                               float* __restrict__ er) {
    __shared__ float hT[16][132];  // [k][row], padded
    __shared__ float ws[16][128];  // [k][col]
    int t = threadIdx.x;
    int tx = t & 15, ty = t >> 4;
    int rowBase = blockIdx.x * 128;
    float acc[8][8] = {};

    int sr  = t >> 1;           // 0..127 row for A staging
    int sc  = (t & 1) * 8;      // k offset 0 or 8
    int wkk = t >> 4;           // 0..15
    int wjj = (t & 15) * 8;     // 0..120

    float4 va0 = make_float4(0.f, 0.f, 0.f, 0.f), va1 = va0, vw0, vw1;
    {
        int grow = rowBase + sr;
        if (grow < N_NODES) {
            va0 = *(const float4*)&H[(size_t)grow * 256 + sc];
            va1 = *(const float4*)&H[(size_t)grow * 256 + sc + 4];
        }
        vw0 = *(const float4*)&W[(size_t)wkk * 128 + wjj];
        vw1 = *(const float4*)&W[(size_t)wkk * 128 + wjj + 4];
    }

    for (int k0 = 0; k0 < 256; k0 += 16) {
        __syncthreads();
        hT[sc + 0][sr] = va0.x; hT[sc + 1][sr] = va0.y;
        hT[sc + 2][sr] = va0.z; hT[sc + 3][sr] = va0.w;
        hT[sc + 4][sr] = va1.x; hT[sc + 5][sr] = va1.y;
        hT[sc + 6][sr] = va1.z; hT[sc + 7][sr] = va1.w;
        *(float4*)&ws[wkk][wjj]     = vw0;
        *(float4*)&ws[wkk][wjj + 4] = vw1;
        __syncthreads();

        if (k0 + 16 < 256) {
            int k1 = k0 + 16;
            va0 = make_float4(0.f, 0.f, 0.f, 0.f); va1 = va0;
            int grow = rowBase + sr;
            if (grow < N_NODES) {
                va0 = *(const float4*)&H[(size_t)grow * 256 + k1 + sc];
                va1 = *(const float4*)&H[(size_t)grow * 256 + k1 + sc + 4];
            }
            vw0 = *(const float4*)&W[(size_t)(k1 + wkk) * 128 + wjj];
            vw1 = *(const float4*)&W[(size_t)(k1 + wkk) * 128 + wjj + 4];
        }

        #pragma unroll
        for (int k = 0; k < 16; ++k) {
            float a[8], b[8];
            *(float4*)&a[0] = *(const float4*)&hT[k][ty * 8];
            *(float4*)&a[4] = *(const float4*)&hT[k][ty * 8 + 4];
            *(float4*)&b[0] = *(const float4*)&ws[k][tx * 4];
            *(float4*)&b[4] = *(const float4*)&ws[k][64 + tx * 4];
            #pragma unroll
            for (int i = 0; i < 8; ++i)
                #pragma unroll
                for (int j = 0; j < 8; ++j)
                    acc[i][j] = fmaf(a[i], b[j], acc[i][j]);
        }
    }

    // bf16 feature rows
    #pragma unroll
    for (int i = 0; i < 8; ++i) {
        int row = rowBase + ty * 8 + i;
        if (row < N_NODES) {
            ushort4 p0 = {f2bf(acc[i][0]), f2bf(acc[i][1]), f2bf(acc[i][2]), f2bf(acc[i][3])};
            ushort4 p1 = {f2bf(acc[i][4]), f2bf(acc[i][5]), f2bf(acc[i][6]), f2bf(acc[i][7])};
            *(ushort4*)&Fb[(size_t)row * 128 + tx * 4]      = p0;
            *(ushort4*)&Fb[(size_t)row * 128 + 64 + tx * 4] = p1;
        }
    }

    // fused el/er: this thread's cols are head hA (lo 4) and head hB (hi 4)
    int hA = tx >> 3, hB = 2 + (tx >> 3);
    int ao = (tx & 7) * 4;
    float elA[8], erA[8], elB[8], erB[8];
    #pragma unroll
    for (int i = 0; i < 8; ++i) {
        float a0 = 0.f, r0 = 0.f, a1 = 0.f, r1 = 0.f;
        #pragma unroll
        for (int c = 0; c < 4; ++c) {
            a0 = fmaf(acc[i][c],     AL[hA * 32 + ao + c], a0);
            r0 = fmaf(acc[i][c],     AR[hA * 32 + ao + c], r0);
            a1 = fmaf(acc[i][4 + c], AL[hB * 32 + ao + c], a1);
            r1 = fmaf(acc[i][4 + c], AR[hB * 32 + ao + c], r1);
        }
        elA[i] = a0; erA[i] = r0; elB[i] = a1; erB[i] = r1;
    }
    #pragma unroll
    for (int m = 1; m <= 4; m <<= 1) {
        #pragma unroll
        for (int i = 0; i < 8; ++i) {
            elA[i] += __shfl_xor(elA[i], m, 64);
            erA[i] += __shfl_xor(erA[i], m, 64);
            elB[i] += __shfl_xor(elB[i], m, 64);
            erB[i] += __shfl_xor(erB[i], m, 64);
        }
    }
    if ((tx & 7) == 0) {
        #pragma unroll
        for (int i = 0; i < 8; ++i) {
            int row = rowBase + ty * 8 + i;
            if (row < N_NODES) {
                el[(size_t)row * 4 + hA] = elA[i];
                er[(size_t)row * 4 + hA] = erA[i];
                el[(size_t)row * 4 + hB] = elB[i];
                er[(size_t)row * 4 + hB] = erB[i];
            }
        }
    }
}

// ---------------- agg1: LDS-staged edges + pipelined gathers ----------------
// block = 256 thr = 4 waves = 4 nodes; wave lanes: g = edge slot (4), l = dim group (16)

__global__ __launch_bounds__(256) void agg1_k(const unsigned short* __restrict__ Fb,
                                              const int* __restrict__ off,
                                              const int* __restrict__ csr,
                                              const float* __restrict__ wb1,
                                              const float* __restrict__ b1,
                                              const float* __restrict__ W2,
                                              const float* __restrict__ al2,
                                              const float* __restrict__ ar2,
                                              unsigned short* __restrict__ feat2b,
                                              float* __restrict__ el2,
                                              float* __restrict__ er2) {
    __shared__ int   sidx[MAXE_BLK];
    __shared__ float swt[MAXE_BLK][4];
    __shared__ float h1row[4][128];
    __shared__ int   soff[5];
    int tid = threadIdx.x;
    int nb = blockIdx.x * 4;
    if (tid < 5) soff[tid] = off[nb + tid];
    __syncthreads();
    int base = soff[0];
    int tot  = soff[4] - base;
    int stg  = tot < MAXE_BLK ? tot : MAXE_BLK;
    for (int i = tid; i < stg; i += 256) {
        sidx[i] = csr[base + i];
        *(float4*)&swt[i][0] = *(const float4*)&wb1[(size_t)(base + i) * 4];
    }
    __syncthreads();

    int wid = tid >> 6;
    int t = tid & 63;
    int g = t >> 4;        // edge slot 0..3
    int l = t & 15;        // dims 8l..8l+7
    int hh = l >> 2;       // head
    int e1 = soff[wid + 1] - base;
    int e  = soff[wid] - base + g;

    float a0 = 0.f, a1 = 0.f, a2 = 0.f, a3 = 0.f, a4 = 0.f, a5 = 0.f, a6 = 0.f, a7 = 0.f;
    float dsum = 0.f;

    float wC = 0.f;
    uint4 uC = {0u, 0u, 0u, 0u};
    if (e < e1) {
        int sC;
        if (e < stg) { sC = sidx[e]; wC = swt[e][hh]; }
        else { sC = csr[base + e]; wC = wb1[(size_t)(base + e) * 4 + hh]; }
        uC = *(const uint4*)&Fb[(size_t)sC * 128 + l * 8];
    }
    while (e < e1) {
        int en = e + 4;
        float wN = 0.f;
        uint4 uN = {0u, 0u, 0u, 0u};
        if (en < e1) {
            int sN;
            if (en < stg) { sN = sidx[en]; wN = swt[en][hh]; }
            else { sN = csr[base + en]; wN = wb1[(size_t)(base + en) * 4 + hh]; }
            uN = *(const uint4*)&Fb[(size_t)sN * 128 + l * 8];
        }
        a0 = fmaf(wC, bflo(uC.x), a0); a1 = fmaf(wC, bfhi(uC.x), a1);
        a2 = fmaf(wC, bflo(uC.y), a2); a3 = fmaf(wC, bfhi(uC.y), a3);
        a4 = fmaf(wC, bflo(uC.z), a4); a5 = fmaf(wC, bfhi(uC.z), a5);
        a6 = fmaf(wC, bflo(uC.w), a6); a7 = fmaf(wC, bfhi(uC.w), a7);
        dsum += wC;
        e = en; wC = wN; uC = uN;
    }
    #pragma unroll
    for (int m = 16; m <= 32; m <<= 1) {
        a0 += __shfl_xor(a0, m, 64); a1 += __shfl_xor(a1, m, 64);
        a2 += __shfl_xor(a2, m, 64); a3 += __shfl_xor(a3, m, 64);
        a4 += __shfl_xor(a4, m, 64); a5 += __shfl_xor(a5, m, 64);
        a6 += __shfl_xor(a6, m, 64); a7 += __shfl_xor(a7, m, 64);
        dsum += __shfl_xor(dsum, m, 64);
    }

    float inv = 1.f / (dsum + EPS_DEN);
    float o[8] = {a0, a1, a2, a3, a4, a5, a6, a7};
    #pragma unroll
    for (int j = 0; j < 8; ++j) {
        float v = fmaf(o[j], inv, b1[l * 8 + j]);
        o[j] = v > 0.f ? v : expm1f(v);
    }
    if (g == 0) {
        *(float4*)&h1row[wid][l * 8]     = make_float4(o[0], o[1], o[2], o[3]);
        *(float4*)&h1row[wid][l * 8 + 4] = make_float4(o[4], o[5], o[6], o[7]);
    }
    // wave-coherent LDS RAW within the same wave

    int j = t & 31, halfk = t >> 5;
    float part = 0.f;
    int kb = halfk << 6;
    #pragma unroll 8
    for (int k = 0; k < 64; ++k)
        part = fmaf(h1row[wid][kb + k], W2[(size_t)(kb + k) * 32 + j], part);
    part += __shfl_xor(part, 32, 64);

    int n = nb + wid;
    if (t < 32 && n < N_NODES) {
        feat2b[(size_t)n * 32 + j] = f2bf(part);
        float sl = part * al2[j];
        float sr = part * ar2[j];
        #pragma unroll
        for (int m = 16; m >= 1; m >>= 1) {
            sl += __shfl_xor(sl, m, 64);
            sr += __shfl_xor(sr, m, 64);
        }
        if (j == 0) { el2[n] = sl; er2[n] = sr; }
    }
}

// ---------------- layer-2 edge weights ----------------

__global__ void w2_k(const int* __restrict__ src, const int* __restrict__ dst,
                     const int* __restrict__ perm, const float* __restrict__ el2,
                     const float* __restrict__ er2, float* __restrict__ w2buf) {
    int e = blockIdx.x * 256 + threadIdx.x;
    if (e >= N_EDGES) return;
    float x = el2[src[e]] + er2[dst[e]];
    x = x > 0.f ? x : NEG_SLOPE * x;
    w2buf[perm[e]] = __expf(x);
}

// ---------------- agg2: wave-per-node, 16 edge slots x 4 lanes (bf16x8) ----------------

__global__ __launch_bounds__(256) void agg2_k(const unsigned short* __restrict__ F2b,
                                              const int* __restrict__ off,
                                              const int* __restrict__ csr,
                                              const float* __restrict__ w2,
                                              const float* __restrict__ b2,
                                              float* __restrict__ out) {
    int wid = threadIdx.x >> 6;
    int n = blockIdx.x * 4 + wid;
    if (n >= N_NODES) return;
    int t = threadIdx.x & 63;
    int g = t >> 2, l = t & 3;   // dims 8l..8l+7
    int e0 = off[n], e1 = off[n + 1];

    float a0 = 0.f, a1 = 0.f, a2 = 0.f, a3 = 0.f, a4 = 0.f, a5 = 0.f, a6 = 0.f, a7 = 0.f;
    float dsum = 0.f;
    for (int e = e0 + g; e < e1; e += 16) {
        int s = csr[e];
        float w = w2[e];
        uint4 u = *(const uint4*)&F2b[(size_t)s * 32 + l * 8];
        a0 = fmaf(w, bflo(u.x), a0); a1 = fmaf(w, bfhi(u.x), a1);
        a2 = fmaf(w, bflo(u.y), a2); a3 = fmaf(w, bfhi(u.y), a3);
        a4 = fmaf(w, bflo(u.z), a4); a5 = fmaf(w, bfhi(u.z), a5);
        a6 = fmaf(w, bflo(u.w), a6); a7 = fmaf(w, bfhi(u.w), a7);
        dsum += w;
    }
    #pragma unroll
    for (int m = 4; m <= 32; m <<= 1) {
        a0 += __shfl_xor(a0, m, 64); a1 += __shfl_xor(a1, m, 64);
        a2 += __shfl_xor(a2, m, 64); a3 += __shfl_xor(a3, m, 64);
        a4 += __shfl_xor(a4, m, 64); a5 += __shfl_xor(a5, m, 64);
        a6 += __shfl_xor(a6, m, 64); a7 += __shfl_xor(a7, m, 64);
        dsum += __shfl_xor(dsum, m, 64);
    }
    if (t < 4) {
        float inv = 1.f / (dsum + EPS_DEN);
        float4 r0, r1;
        r0.x = fmaf(a0, inv, b2[l * 8 + 0]);
        r0.y = fmaf(a1, inv, b2[l * 8 + 1]);
        r0.z = fmaf(a2, inv, b2[l * 8 + 2]);
        r0.w = fmaf(a3, inv, b2[l * 8 + 3]);
        r1.x = fmaf(a4, inv, b2[l * 8 + 4]);
        r1.y = fmaf(a5, inv, b2[l * 8 + 5]);
        r1.z = fmaf(a6, inv, b2[l * 8 + 6]);
        r1.w = fmaf(a7, inv, b2[l * 8 + 7]);
        *(float4*)&out[(size_t)n * 32 + l * 8]     = r0;
        *(float4*)&out[(size_t)n * 32 + l * 8 + 4] = r1;
    }
}

// ---------------- launch ----------------

extern "C" void kernel_launch(void* const* d_in, const int* in_sizes, int n_in,
                              void* d_out, int out_size, void* d_ws, size_t ws_size,
                              hipStream_t stream) {
    const float* h   = (const float*)d_in[0];
    const float* W1  = (const float*)d_in[1];
    const float* al1 = (const float*)d_in[2];
    const float* ar1 = (const float*)d_in[3];
    const float* b1  = (const float*)d_in[4];
    const float* W2  = (const float*)d_in[5];
    const float* al2 = (const float*)d_in[6];
    const float* ar2 = (const float*)d_in[7];
    const float* b2  = (const float*)d_in[8];
    const int* src   = (const int*)d_in[9];
    const int* dst   = (const int*)d_in[10];
    float* out = (float*)d_out;

    char* wsb = (char*)d_ws;
    size_t o = 0;
    auto alloc = [&](size_t bytes) {
        void* p = wsb + o;
        o += (bytes + 255) & ~(size_t)255;
        return p;
    };
    int* deg     = (int*)alloc((size_t)N_NODES * 4);
    int* off     = (int*)alloc((size_t)(N_NODES + 1) * 4);
    int* cursor  = (int*)alloc((size_t)N_NODES * 4);
    int* csr     = (int*)alloc((size_t)N_EDGES * 4);
    int* perm    = (int*)alloc((size_t)N_EDGES * 4);
    int* bsum    = (int*)alloc((size_t)NB_SCAN * 4);
    unsigned short* feat1b = (unsigned short*)alloc((size_t)N_NODES * 128 * 2);
    float* el1   = (float*)alloc((size_t)N_NODES * 4 * 4);
    float* er1   = (float*)alloc((size_t)N_NODES * 4 * 4);
    float* wb1   = (float*)alloc((size_t)N_EDGES * 4 * 4);
    unsigned short* feat2b = (unsigned short*)alloc((size_t)N_NODES * 32 * 2);
    float* el2   = (float*)alloc((size_t)N_NODES * 4);
    float* er2   = (float*)alloc((size_t)N_NODES * 4);
    float* w2buf = wb1;  // reuse: wb1 dead after agg1

    hipMemsetAsync(deg, 0, (size_t)N_NODES * 4, stream);
    count_k<<<(N_EDGES + 255) / 256, 256, 0, stream>>>(dst, deg);
    scan1_k<<<NB_SCAN, 256, 0, stream>>>(deg, off, bsum);
    scan3_k<<<(N_NODES + 255) / 256, 256, 0, stream>>>(off, bsum);
    hipMemcpyAsync(cursor, off, (size_t)N_NODES * 4, hipMemcpyDeviceToDevice, stream);
    gemm1_k<<<(N_NODES + 127) / 128, 256, 0, stream>>>(h, W1, al1, ar1, feat1b, el1, er1);
    scatter_k<<<(N_EDGES + 255) / 256, 256, 0, stream>>>(src, dst, cursor, csr, perm,
                                                         el1, er1, wb1);
    agg1_k<<<(N_NODES + 3) / 4, 256, 0, stream>>>(feat1b, off, csr, wb1, b1, W2,
                                                  al2, ar2, feat2b, el2, er2);
    w2_k<<<(N_EDGES + 255) / 256, 256, 0, stream>>>(src, dst, perm, el2, er2, w2buf);
    agg2_k<<<(N_NODES + 3) / 4, 256, 0, stream>>>(feat2b, off, csr, w2buf, b2, out);
}

// Round 6
// 241.572 us; speedup vs baseline: 1.1603x; 1.1603x over previous
//
#include <hip/hip_runtime.h>
#include <hip/hip_bf16.h>
#include <math.h>

#define N_NODES 50000
#define N_EDGES 800000
#define NEG_SLOPE 0.2f
#define EPS_DEN 1e-9f

constexpr int SCAN_BLK = 1024;
constexpr int NB_SCAN = (N_NODES + SCAN_BLK - 1) / SCAN_BLK; // 49

__device__ inline unsigned short f2bf(float x) {
    __hip_bfloat16 h = __float2bfloat16(x);
    return *(unsigned short*)&h;
}
__device__ inline float bflo(unsigned int u) { return __uint_as_float(u << 16); }
__device__ inline float bfhi(unsigned int u) { return __uint_as_float(u & 0xffff0000u); }

// ---------------- CSR build ----------------

__global__ void count_k(const int* __restrict__ dst, int* __restrict__ deg) {
    int e = blockIdx.x * 256 + threadIdx.x;
    if (e < N_EDGES) atomicAdd(&deg[dst[e]], 1);
}

__global__ void scan1_k(const int* __restrict__ deg, int* __restrict__ off,
                        int* __restrict__ bsum) {
    __shared__ int sh[256];
    int b = blockIdx.x, t = threadIdx.x;
    int base = b * SCAN_BLK + t * 4;
    int v[4]; int s = 0;
    #pragma unroll
    for (int i = 0; i < 4; ++i) {
        int idx = base + i;
        v[i] = (idx < N_NODES) ? deg[idx] : 0;
        s += v[i];
    }
    sh[t] = s; __syncthreads();
    for (int ofs = 1; ofs < 256; ofs <<= 1) {
        int x = 0;
        if (t >= ofs) x = sh[t - ofs];
        __syncthreads();
        sh[t] += x;
        __syncthreads();
    }
    int excl = sh[t] - s;
    if (t == 255) bsum[b] = sh[255];
    int run = excl;
    #pragma unroll
    for (int i = 0; i < 4; ++i) {
        int idx = base + i;
        if (idx < N_NODES) off[idx] = run;
        run += v[i];
    }
}

// merged scan2+scan3
__global__ void scan3_k(int* __restrict__ off, const int* __restrict__ bsum) {
    __shared__ int pre;
    int b = blockIdx.x;
    if (threadIdx.x == 0) {
        int s = 0;
        int nb = b >> 2;
        for (int j = 0; j < nb; ++j) s += bsum[j];
        pre = s;
    }
    __syncthreads();
    int i = b * 256 + threadIdx.x;
    if (i < N_NODES) off[i] += pre;
    if (i == 0) off[N_NODES] = N_EDGES;
}

// scatter + layer-1 edge weights
__global__ void scatter_k(const int* __restrict__ src, const int* __restrict__ dst,
                          int* __restrict__ cursor, int* __restrict__ csr,
                          int* __restrict__ perm,
                          const float* __restrict__ el1, const float* __restrict__ er1,
                          float* __restrict__ wb1) {
    int e = blockIdx.x * 256 + threadIdx.x;
    if (e >= N_EDGES) return;
    int s = src[e], d = dst[e];
    int p = atomicAdd(&cursor[d], 1);
    csr[p] = s;
    perm[e] = p;
    float4 a = *(const float4*)&el1[(size_t)s * 4];
    float4 b = *(const float4*)&er1[(size_t)d * 4];
    float4 x = make_float4(a.x + b.x, a.y + b.y, a.z + b.z, a.w + b.w);
    x.x = x.x > 0.f ? x.x : NEG_SLOPE * x.x;
    x.y = x.y > 0.f ? x.y : NEG_SLOPE * x.y;
    x.z = x.z > 0.f ? x.z : NEG_SLOPE * x.z;
    x.w = x.w > 0.f ? x.w : NEG_SLOPE * x.w;
    float4 w = make_float4(__expf(x.x), __expf(x.y), __expf(x.z), __expf(x.w));
    *(float4*)&wb1[(size_t)p * 4] = w;
}

// ---------------- GEMM1 + fused el1/er1 + bf16 feat1 out ----------------
// 128x128 tile / 256 threads, 8x8 microtile. t = ty*16+tx.

__global__ __launch_bounds__(256) void gemm1_k(const float* __restrict__ H,
                                               const float* __restrict__ W,
                                               const float* __restrict__ AL,
                                               const float* __restrict__ AR,
                                               unsigned short* __restrict__ Fb,
                                               float* __restrict__ el,
                                               float* __restrict__ er) {
    __shared__ float hT[16][132];  // [k][row], padded
    __shared__ float ws[16][128];  // [k][col]
    int t = threadIdx.x;
    int tx = t & 15, ty = t >> 4;
    int rowBase = blockIdx.x * 128;
    float acc[8][8] = {};

    int sr  = t >> 1;           // 0..127 row for A staging
    int sc  = (t & 1) * 8;      // k offset 0 or 8
    int wkk = t >> 4;           // 0..15
    int wjj = (t & 15) * 8;     // 0..120

    float4 va0 = make_float4(0.f, 0.f, 0.f, 0.f), va1 = va0, vw0, vw1;
    {
        int grow = rowBase + sr;
        if (grow < N_NODES) {
            va0 = *(const float4*)&H[(size_t)grow * 256 + sc];
            va1 = *(const float4*)&H[(size_t)grow * 256 + sc + 4];
        }
        vw0 = *(const float4*)&W[(size_t)wkk * 128 + wjj];
        vw1 = *(const float4*)&W[(size_t)wkk * 128 + wjj + 4];
    }

    for (int k0 = 0; k0 < 256; k0 += 16) {
        __syncthreads();
        hT[sc + 0][sr] = va0.x; hT[sc + 1][sr] = va0.y;
        hT[sc + 2][sr] = va0.z; hT[sc + 3][sr] = va0.w;
        hT[sc + 4][sr] = va1.x; hT[sc + 5][sr] = va1.y;
        hT[sc + 6][sr] = va1.z; hT[sc + 7][sr] = va1.w;
        *(float4*)&ws[wkk][wjj]     = vw0;
        *(float4*)&ws[wkk][wjj + 4] = vw1;
        __syncthreads();

        if (k0 + 16 < 256) {
            int k1 = k0 + 16;
            va0 = make_float4(0.f, 0.f, 0.f, 0.f); va1 = va0;
            int grow = rowBase + sr;
            if (grow < N_NODES) {
                va0 = *(const float4*)&H[(size_t)grow * 256 + k1 + sc];
                va1 = *(const float4*)&H[(size_t)grow * 256 + k1 + sc + 4];
            }
            vw0 = *(const float4*)&W[(size_t)(k1 + wkk) * 128 + wjj];
            vw1 = *(const float4*)&W[(size_t)(k1 + wkk) * 128 + wjj + 4];
        }

        #pragma unroll
        for (int k = 0; k < 16; ++k) {
            float a[8], b[8];
            *(float4*)&a[0] = *(const float4*)&hT[k][ty * 8];
            *(float4*)&a[4] = *(const float4*)&hT[k][ty * 8 + 4];
            *(float4*)&b[0] = *(const float4*)&ws[k][tx * 4];
            *(float4*)&b[4] = *(const float4*)&ws[k][64 + tx * 4];
            #pragma unroll
            for (int i = 0; i < 8; ++i)
                #pragma unroll
                for (int j = 0; j < 8; ++j)
                    acc[i][j] = fmaf(a[i], b[j], acc[i][j]);
        }
    }

    // bf16 feature rows
    #pragma unroll
    for (int i = 0; i < 8; ++i) {
        int row = rowBase + ty * 8 + i;
        if (row < N_NODES) {
            ushort4 p0 = {f2bf(acc[i][0]), f2bf(acc[i][1]), f2bf(acc[i][2]), f2bf(acc[i][3])};
            ushort4 p1 = {f2bf(acc[i][4]), f2bf(acc[i][5]), f2bf(acc[i][6]), f2bf(acc[i][7])};
            *(ushort4*)&Fb[(size_t)row * 128 + tx * 4]      = p0;
            *(ushort4*)&Fb[(size_t)row * 128 + 64 + tx * 4] = p1;
        }
    }

    // fused el/er
    int hA = tx >> 3, hB = 2 + (tx >> 3);
    int ao = (tx & 7) * 4;
    float elA[8], erA[8], elB[8], erB[8];
    #pragma unroll
    for (int i = 0; i < 8; ++i) {
        float a0 = 0.f, r0 = 0.f, a1 = 0.f, r1 = 0.f;
        #pragma unroll
        for (int c = 0; c < 4; ++c) {
            a0 = fmaf(acc[i][c],     AL[hA * 32 + ao + c], a0);
            r0 = fmaf(acc[i][c],     AR[hA * 32 + ao + c], r0);
            a1 = fmaf(acc[i][4 + c], AL[hB * 32 + ao + c], a1);
            r1 = fmaf(acc[i][4 + c], AR[hB * 32 + ao + c], r1);
        }
        elA[i] = a0; erA[i] = r0; elB[i] = a1; erB[i] = r1;
    }
    #pragma unroll
    for (int m = 1; m <= 4; m <<= 1) {
        #pragma unroll
        for (int i = 0; i < 8; ++i) {
            elA[i] += __shfl_xor(elA[i], m, 64);
            erA[i] += __shfl_xor(erA[i], m, 64);
            elB[i] += __shfl_xor(elB[i], m, 64);
            erB[i] += __shfl_xor(erB[i], m, 64);
        }
    }
    if ((tx & 7) == 0) {
        #pragma unroll
        for (int i = 0; i < 8; ++i) {
            int row = rowBase + ty * 8 + i;
            if (row < N_NODES) {
                el[(size_t)row * 4 + hA] = elA[i];
                er[(size_t)row * 4 + hA] = erA[i];
                el[(size_t)row * 4 + hB] = elB[i];
                er[(size_t)row * 4 + hB] = erB[i];
            }
        }
    }
}

// ---------------- agg1: wave-per-node, pair-pipelined gathers ----------------
// wave lanes: g = slot 0..3, l = dim group 0..15 (dims 8l..8l+7), head l>>2.
// Each iteration handles 8 edges (slots e+g and e+g+4), prefetching next 8.

__global__ __launch_bounds__(256) void agg1_k(const unsigned short* __restrict__ Fb,
                                              const int* __restrict__ off,
                                              const int* __restrict__ csr,
                                              const float* __restrict__ wb1,
                                              const float* __restrict__ b1,
                                              const float* __restrict__ W2,
                                              const float* __restrict__ al2,
                                              const float* __restrict__ ar2,
                                              unsigned short* __restrict__ feat2b,
                                              float* __restrict__ el2,
                                              float* __restrict__ er2) {
    __shared__ float h1row[4][128];
    int wid = threadIdx.x >> 6;
    int n = blockIdx.x * 4 + wid;
    if (n >= N_NODES) return;
    int t = threadIdx.x & 63;
    int g = t >> 4;
    int l = t & 15;
    int hh = l >> 2;
    int e0 = off[n], e1 = off[n + 1];

    float a0 = 0.f, a1 = 0.f, a2 = 0.f, a3 = 0.f, a4 = 0.f, a5 = 0.f, a6 = 0.f, a7 = 0.f;
    float dsum = 0.f;

    int eA = e0 + g, eB = eA + 4;
    float wA = 0.f, wB = 0.f;
    uint4 uA = {0u,0u,0u,0u}, uB = {0u,0u,0u,0u};
    if (eA < e1) {
        int s = csr[eA]; wA = wb1[(size_t)eA * 4 + hh];
        uA = *(const uint4*)&Fb[(size_t)s * 128 + l * 8];
    }
    if (eB < e1) {
        int s = csr[eB]; wB = wb1[(size_t)eB * 4 + hh];
        uB = *(const uint4*)&Fb[(size_t)s * 128 + l * 8];
    }

    for (int e = eA; e < e1; e += 8) {
        int nA = e + 8, nB = e + 12;
        float wA2 = 0.f, wB2 = 0.f;
        uint4 uA2 = {0u,0u,0u,0u}, uB2 = {0u,0u,0u,0u};
        if (nA < e1) {
            int s = csr[nA]; wA2 = wb1[(size_t)nA * 4 + hh];
            uA2 = *(const uint4*)&Fb[(size_t)s * 128 + l * 8];
        }
        if (nB < e1) {
            int s = csr[nB]; wB2 = wb1[(size_t)nB * 4 + hh];
            uB2 = *(const uint4*)&Fb[(size_t)s * 128 + l * 8];
        }
        a0 = fmaf(wA, bflo(uA.x), a0); a1 = fmaf(wA, bfhi(uA.x), a1);
        a2 = fmaf(wA, bflo(uA.y), a2); a3 = fmaf(wA, bfhi(uA.y), a3);
        a4 = fmaf(wA, bflo(uA.z), a4); a5 = fmaf(wA, bfhi(uA.z), a5);
        a6 = fmaf(wA, bflo(uA.w), a6); a7 = fmaf(wA, bfhi(uA.w), a7);
        a0 = fmaf(wB, bflo(uB.x), a0); a1 = fmaf(wB, bfhi(uB.x), a1);
        a2 = fmaf(wB, bflo(uB.y), a2); a3 = fmaf(wB, bfhi(uB.y), a3);
        a4 = fmaf(wB, bflo(uB.z), a4); a5 = fmaf(wB, bfhi(uB.z), a5);
        a6 = fmaf(wB, bflo(uB.w), a6); a7 = fmaf(wB, bfhi(uB.w), a7);
        dsum += wA + wB;
        uA = uA2; uB = uB2; wA = wA2; wB = wB2;
    }

    #pragma unroll
    for (int m = 16; m <= 32; m <<= 1) {
        a0 += __shfl_xor(a0, m, 64); a1 += __shfl_xor(a1, m, 64);
        a2 += __shfl_xor(a2, m, 64); a3 += __shfl_xor(a3, m, 64);
        a4 += __shfl_xor(a4, m, 64); a5 += __shfl_xor(a5, m, 64);
        a6 += __shfl_xor(a6, m, 64); a7 += __shfl_xor(a7, m, 64);
        dsum += __shfl_xor(dsum, m, 64);
    }

    float inv = 1.f / (dsum + EPS_DEN);
    float o[8] = {a0, a1, a2, a3, a4, a5, a6, a7};
    #pragma unroll
    for (int j = 0; j < 8; ++j) {
        float v = fmaf(o[j], inv, b1[l * 8 + j]);
        o[j] = v > 0.f ? v : __expf(v) - 1.f;
    }
    if (g == 0) {
        *(float4*)&h1row[wid][l * 8]     = make_float4(o[0], o[1], o[2], o[3]);
        *(float4*)&h1row[wid][l * 8 + 4] = make_float4(o[4], o[5], o[6], o[7]);
    }
    // wave-coherent LDS RAW within the same wave

    int j = t & 31, halfk = t >> 5;
    float part = 0.f;
    int kb = halfk << 6;
    #pragma unroll 8
    for (int k = 0; k < 64; ++k)
        part = fmaf(h1row[wid][kb + k], W2[(size_t)(kb + k) * 32 + j], part);
    part += __shfl_xor(part, 32, 64);

    if (t < 32) {
        feat2b[(size_t)n * 32 + j] = f2bf(part);
        float sl = part * al2[j];
        float sr = part * ar2[j];
        #pragma unroll
        for (int m = 16; m >= 1; m >>= 1) {
            sl += __shfl_xor(sl, m, 64);
            sr += __shfl_xor(sr, m, 64);
        }
        if (j == 0) { el2[n] = sl; er2[n] = sr; }
    }
}

// ---------------- layer-2 edge weights ----------------

__global__ void w2_k(const int* __restrict__ src, const int* __restrict__ dst,
                     const int* __restrict__ perm, const float* __restrict__ el2,
                     const float* __restrict__ er2, float* __restrict__ w2buf) {
    int e = blockIdx.x * 256 + threadIdx.x;
    if (e >= N_EDGES) return;
    float x = el2[src[e]] + er2[dst[e]];
    x = x > 0.f ? x : NEG_SLOPE * x;
    w2buf[perm[e]] = __expf(x);
}

// ---------------- agg2: wave-per-node, 16 edge slots x 4 lanes (bf16x8) ----------------

__global__ __launch_bounds__(256) void agg2_k(const unsigned short* __restrict__ F2b,
                                              const int* __restrict__ off,
                                              const int* __restrict__ csr,
                                              const float* __restrict__ w2,
                                              const float* __restrict__ b2,
                                              float* __restrict__ out) {
    int wid = threadIdx.x >> 6;
    int n = blockIdx.x * 4 + wid;
    if (n >= N_NODES) return;
    int t = threadIdx.x & 63;
    int g = t >> 2, l = t & 3;   // dims 8l..8l+7
    int e0 = off[n], e1 = off[n + 1];

    float a0 = 0.f, a1 = 0.f, a2 = 0.f, a3 = 0.f, a4 = 0.f, a5 = 0.f, a6 = 0.f, a7 = 0.f;
    float dsum = 0.f;
    for (int e = e0 + g; e < e1; e += 16) {
        int s = csr[e];
        float w = w2[e];
        uint4 u = *(const uint4*)&F2b[(size_t)s * 32 + l * 8];
        a0 = fmaf(w, bflo(u.x), a0); a1 = fmaf(w, bfhi(u.x), a1);
        a2 = fmaf(w, bflo(u.y), a2); a3 = fmaf(w, bfhi(u.y), a3);
        a4 = fmaf(w, bflo(u.z), a4); a5 = fmaf(w, bfhi(u.z), a5);
        a6 = fmaf(w, bflo(u.w), a6); a7 = fmaf(w, bfhi(u.w), a7);
        dsum += w;
    }
    #pragma unroll
    for (int m = 4; m <= 32; m <<= 1) {
        a0 += __shfl_xor(a0, m, 64); a1 += __shfl_xor(a1, m, 64);
        a2 += __shfl_xor(a2, m, 64); a3 += __shfl_xor(a3, m, 64);
        a4 += __shfl_xor(a4, m, 64); a5 += __shfl_xor(a5, m, 64);
        a6 += __shfl_xor(a6, m, 64); a7 += __shfl_xor(a7, m, 64);
        dsum += __shfl_xor(dsum, m, 64);
    }
    if (t < 4) {
        float inv = 1.f / (dsum + EPS_DEN);
        float4 r0, r1;
        r0.x = fmaf(a0, inv, b2[l * 8 + 0]);
        r0.y = fmaf(a1, inv, b2[l * 8 + 1]);
        r0.z = fmaf(a2, inv, b2[l * 8 + 2]);
        r0.w = fmaf(a3, inv, b2[l * 8 + 3]);
        r1.x = fmaf(a4, inv, b2[l * 8 + 4]);
        r1.y = fmaf(a5, inv, b2[l * 8 + 5]);
        r1.z = fmaf(a6, inv, b2[l * 8 + 6]);
        r1.w = fmaf(a7, inv, b2[l * 8 + 7]);
        *(float4*)&out[(size_t)n * 32 + l * 8]     = r0;
        *(float4*)&out[(size_t)n * 32 + l * 8 + 4] = r1;
    }
}

// ---------------- launch ----------------

extern "C" void kernel_launch(void* const* d_in, const int* in_sizes, int n_in,
                              void* d_out, int out_size, void* d_ws, size_t ws_size,
                              hipStream_t stream) {
    const float* h   = (const float*)d_in[0];
    const float* W1  = (const float*)d_in[1];
    const float* al1 = (const float*)d_in[2];
    const float* ar1 = (const float*)d_in[3];
    const float* b1  = (const float*)d_in[4];
    const float* W2  = (const float*)d_in[5];
    const float* al2 = (const float*)d_in[6];
    const float* ar2 = (const float*)d_in[7];
    const float* b2  = (const float*)d_in[8];
    const int* src   = (const int*)d_in[9];
    const int* dst   = (const int*)d_in[10];
    float* out = (float*)d_out;

    char* wsb = (char*)d_ws;
    size_t o = 0;
    auto alloc = [&](size_t bytes) {
        void* p = wsb + o;
        o += (bytes + 255) & ~(size_t)255;
        return p;
    };
    int* deg     = (int*)alloc((size_t)N_NODES * 4);
    int* off     = (int*)alloc((size_t)(N_NODES + 1) * 4);
    int* cursor  = (int*)alloc((size_t)N_NODES * 4);
    int* csr     = (int*)alloc((size_t)N_EDGES * 4);
    int* perm    = (int*)alloc((size_t)N_EDGES * 4);
    int* bsum    = (int*)alloc((size_t)NB_SCAN * 4);
    unsigned short* feat1b = (unsigned short*)alloc((size_t)N_NODES * 128 * 2);
    float* el1   = (float*)alloc((size_t)N_NODES * 4 * 4);
    float* er1   = (float*)alloc((size_t)N_NODES * 4 * 4);
    float* wb1   = (float*)alloc((size_t)N_EDGES * 4 * 4);
    unsigned short* feat2b = (unsigned short*)alloc((size_t)N_NODES * 32 * 2);
    float* el2   = (float*)alloc((size_t)N_NODES * 4);
    float* er2   = (float*)alloc((size_t)N_NODES * 4);
    float* w2buf = wb1;  // reuse: wb1 dead after agg1

    hipMemsetAsync(deg, 0, (size_t)N_NODES * 4, stream);
    count_k<<<(N_EDGES + 255) / 256, 256, 0, stream>>>(dst, deg);
    scan1_k<<<NB_SCAN, 256, 0, stream>>>(deg, off, bsum);
    scan3_k<<<(N_NODES + 255) / 256, 256, 0, stream>>>(off, bsum);
    hipMemcpyAsync(cursor, off, (size_t)N_NODES * 4, hipMemcpyDeviceToDevice, stream);
    gemm1_k<<<(N_NODES + 127) / 128, 256, 0, stream>>>(h, W1, al1, ar1, feat1b, el1, er1);
    scatter_k<<<(N_EDGES + 255) / 256, 256, 0, stream>>>(src, dst, cursor, csr, perm,
                                                         el1, er1, wb1);
    agg1_k<<<(N_NODES + 3) / 4, 256, 0, stream>>>(feat1b, off, csr, wb1, b1, W2,
                                                  al2, ar2, feat2b, el2, er2);
    w2_k<<<(N_EDGES + 255) / 256, 256, 0, stream>>>(src, dst, perm, el2, er2, w2buf);
    agg2_k<<<(N_NODES + 3) / 4, 256, 0, stream>>>(feat2b, off, csr, w2buf, b2, out);
}

// Round 7
// 232.392 us; speedup vs baseline: 1.2061x; 1.0395x over previous
//
#include <hip/hip_runtime.h>
#include <hip/hip_bf16.h>
#include <math.h>

#define N_NODES 50000
#define N_EDGES 800000
#define NEG_SLOPE 0.2f
#define EPS_DEN 1e-9f

constexpr int SCAN_BLK = 1024;
constexpr int NB_SCAN = (N_NODES + SCAN_BLK - 1) / SCAN_BLK; // 49

typedef __attribute__((ext_vector_type(8))) short short8v;
typedef __attribute__((ext_vector_type(4))) float f32x4;

__device__ inline unsigned short f2bf(float x) {
    __hip_bfloat16 h = __float2bfloat16(x);
    return *(unsigned short*)&h;
}
__device__ inline float bflo(unsigned int u) { return __uint_as_float(u << 16); }
__device__ inline float bfhi(unsigned int u) { return __uint_as_float(u & 0xffff0000u); }

// ---------------- CSR build ----------------

__global__ void count_k(const int* __restrict__ dst, int* __restrict__ deg) {
    int e = blockIdx.x * 256 + threadIdx.x;
    if (e < N_EDGES) atomicAdd(&deg[dst[e]], 1);
}

__global__ void scan1_k(const int* __restrict__ deg, int* __restrict__ off,
                        int* __restrict__ bsum) {
    __shared__ int sh[256];
    int b = blockIdx.x, t = threadIdx.x;
    int base = b * SCAN_BLK + t * 4;
    int v[4]; int s = 0;
    #pragma unroll
    for (int i = 0; i < 4; ++i) {
        int idx = base + i;
        v[i] = (idx < N_NODES) ? deg[idx] : 0;
        s += v[i];
    }
    sh[t] = s; __syncthreads();
    for (int ofs = 1; ofs < 256; ofs <<= 1) {
        int x = 0;
        if (t >= ofs) x = sh[t - ofs];
        __syncthreads();
        sh[t] += x;
        __syncthreads();
    }
    int excl = sh[t] - s;
    if (t == 255) bsum[b] = sh[255];
    int run = excl;
    #pragma unroll
    for (int i = 0; i < 4; ++i) {
        int idx = base + i;
        if (idx < N_NODES) off[idx] = run;
        run += v[i];
    }
}

// merged scan2+scan3
__global__ void scan3_k(int* __restrict__ off, const int* __restrict__ bsum) {
    __shared__ int pre;
    int b = blockIdx.x;
    if (threadIdx.x == 0) {
        int s = 0;
        int nb = b >> 2;
        for (int j = 0; j < nb; ++j) s += bsum[j];
        pre = s;
    }
    __syncthreads();
    int i = b * 256 + threadIdx.x;
    if (i < N_NODES) off[i] += pre;
    if (i == 0) off[N_NODES] = N_EDGES;
}

// scatter + layer-1 edge weights
__global__ void scatter_k(const int* __restrict__ src, const int* __restrict__ dst,
                          int* __restrict__ cursor, int* __restrict__ csr,
                          int* __restrict__ perm,
                          const float* __restrict__ el1, const float* __restrict__ er1,
                          float* __restrict__ wb1) {
    int e = blockIdx.x * 256 + threadIdx.x;
    if (e >= N_EDGES) return;
    int s = src[e], d = dst[e];
    int p = atomicAdd(&cursor[d], 1);
    csr[p] = s;
    perm[e] = p;
    float4 a = *(const float4*)&el1[(size_t)s * 4];
    float4 b = *(const float4*)&er1[(size_t)d * 4];
    float4 x = make_float4(a.x + b.x, a.y + b.y, a.z + b.z, a.w + b.w);
    x.x = x.x > 0.f ? x.x : NEG_SLOPE * x.x;
    x.y = x.y > 0.f ? x.y : NEG_SLOPE * x.y;
    x.z = x.z > 0.f ? x.z : NEG_SLOPE * x.z;
    x.w = x.w > 0.f ? x.w : NEG_SLOPE * x.w;
    float4 w = make_float4(__expf(x.x), __expf(x.y), __expf(x.z), __expf(x.w));
    *(float4*)&wb1[(size_t)p * 4] = w;
}

// ---------------- prep: Wt[col][k] = bf16(W1[k][col]) ----------------

__global__ void prep_k(const float* __restrict__ W, unsigned short* __restrict__ Wt) {
    int i = blockIdx.x * 256 + threadIdx.x;   // i = col*256 + k
    if (i >= 128 * 256) return;
    int col = i >> 8, k = i & 255;
    Wt[i] = f2bf(W[(size_t)k * 128 + col]);
}

// ---------------- GEMM1 (MFMA, zero-LDS): feat1b = bf16(H @ W1) ----------------
// block = 256 thr = 4 waves; wave w: rows [blk*128 + w*32, +32), all 128 cols.
// A split into hi+lo bf16 so only W carries quantization error.
// Frag layouts (mfma_f32_16x16x32_bf16):
//   A: lane l -> A[row=l&15][k=(l>>4)*8 + i]
//   B: lane l -> B[k=(l>>4)*8 + i][col=l&15]
//   C: lane l, reg r -> C[row=(l>>4)*4 + r][col=l&15]

__global__ __launch_bounds__(256) void gemm1_k(const float* __restrict__ H,
                                               const unsigned short* __restrict__ Wt,
                                               unsigned short* __restrict__ Fb) {
    int t = threadIdx.x;
    int w = t >> 6, l = t & 63;
    int lr = l & 15, lk = l >> 4;
    int rowBase = blockIdx.x * 128 + w * 32;
    f32x4 acc[2][8] = {};

    #pragma unroll 2
    for (int kc = 0; kc < 8; ++kc) {
        int k0 = kc * 32 + lk * 8;
        short8v ah[2], alo[2];
        #pragma unroll
        for (int rf = 0; rf < 2; ++rf) {
            int row = rowBase + rf * 16 + lr;
            float hv[8];
            if (row < N_NODES) {
                float4 x0 = *(const float4*)&H[(size_t)row * 256 + k0];
                float4 x1 = *(const float4*)&H[(size_t)row * 256 + k0 + 4];
                hv[0] = x0.x; hv[1] = x0.y; hv[2] = x0.z; hv[3] = x0.w;
                hv[4] = x1.x; hv[5] = x1.y; hv[6] = x1.z; hv[7] = x1.w;
            } else {
                #pragma unroll
                for (int i = 0; i < 8; ++i) hv[i] = 0.f;
            }
            #pragma unroll
            for (int i = 0; i < 8; ++i) {
                unsigned short hi = f2bf(hv[i]);
                float hif = __uint_as_float((unsigned)hi << 16);
                ah[rf][i]  = (short)hi;
                alo[rf][i] = (short)f2bf(hv[i] - hif);
            }
        }
        #pragma unroll
        for (int cf = 0; cf < 8; ++cf) {
            short8v b = *(const short8v*)&Wt[(size_t)(cf * 16 + lr) * 256 + k0];
            acc[0][cf] = __builtin_amdgcn_mfma_f32_16x16x32_bf16(ah[0],  b, acc[0][cf], 0, 0, 0);
            acc[0][cf] = __builtin_amdgcn_mfma_f32_16x16x32_bf16(alo[0], b, acc[0][cf], 0, 0, 0);
            acc[1][cf] = __builtin_amdgcn_mfma_f32_16x16x32_bf16(ah[1],  b, acc[1][cf], 0, 0, 0);
            acc[1][cf] = __builtin_amdgcn_mfma_f32_16x16x32_bf16(alo[1], b, acc[1][cf], 0, 0, 0);
        }
    }

    #pragma unroll
    for (int rf = 0; rf < 2; ++rf) {
        #pragma unroll
        for (int r = 0; r < 4; ++r) {
            int row = rowBase + rf * 16 + lk * 4 + r;
            if (row < N_NODES) {
                #pragma unroll
                for (int cf = 0; cf < 8; ++cf)
                    Fb[(size_t)row * 128 + cf * 16 + lr] = f2bf(acc[rf][cf][r]);
            }
        }
    }
}

// ---------------- el1/er1 from bf16 feat1 ----------------

__global__ void elr1_k(const unsigned short* __restrict__ Fb,
                       const float* __restrict__ al, const float* __restrict__ ar,
                       float* __restrict__ el, float* __restrict__ er) {
    int i = blockIdx.x * 256 + threadIdx.x;
    if (i >= N_NODES * 4) return;
    int hh = i & 3;
    const unsigned short* f = &Fb[(size_t)(i >> 2) * 128 + hh * 32];
    float sl = 0.f, sr = 0.f;
    #pragma unroll
    for (int q = 0; q < 4; ++q) {
        uint4 u = *(const uint4*)&f[q * 8];
        const float* A = &al[hh * 32 + q * 8];
        const float* B = &ar[hh * 32 + q * 8];
        float v0 = bflo(u.x), v1 = bfhi(u.x), v2 = bflo(u.y), v3 = bfhi(u.y);
        float v4 = bflo(u.z), v5 = bfhi(u.z), v6 = bflo(u.w), v7 = bfhi(u.w);
        sl += v0*A[0] + v1*A[1] + v2*A[2] + v3*A[3] + v4*A[4] + v5*A[5] + v6*A[6] + v7*A[7];
        sr += v0*B[0] + v1*B[1] + v2*B[2] + v3*B[3] + v4*B[4] + v5*B[5] + v6*B[6] + v7*B[7];
    }
    el[i] = sl; er[i] = sr;
}

// ---------------- agg1: wave-per-node, pair-pipelined gathers ----------------

__global__ __launch_bounds__(256) void agg1_k(const unsigned short* __restrict__ Fb,
                                              const int* __restrict__ off,
                                              const int* __restrict__ csr,
                                              const float* __restrict__ wb1,
                                              const float* __restrict__ b1,
                                              const float* __restrict__ W2,
                                              const float* __restrict__ al2,
                                              const float* __restrict__ ar2,
                                              unsigned short* __restrict__ feat2b,
                                              float* __restrict__ el2,
                                              float* __restrict__ er2) {
    __shared__ float h1row[4][128];
    int wid = threadIdx.x >> 6;
    int n = blockIdx.x * 4 + wid;
    if (n >= N_NODES) return;
    int t = threadIdx.x & 63;
    int g = t >> 4;
    int l = t & 15;
    int hh = l >> 2;
    int e0 = off[n], e1 = off[n + 1];

    float a0 = 0.f, a1 = 0.f, a2 = 0.f, a3 = 0.f, a4 = 0.f, a5 = 0.f, a6 = 0.f, a7 = 0.f;
    float dsum = 0.f;

    int eA = e0 + g, eB = eA + 4;
    float wA = 0.f, wB = 0.f;
    uint4 uA = {0u,0u,0u,0u}, uB = {0u,0u,0u,0u};
    if (eA < e1) {
        int s = csr[eA]; wA = wb1[(size_t)eA * 4 + hh];
        uA = *(const uint4*)&Fb[(size_t)s * 128 + l * 8];
    }
    if (eB < e1) {
        int s = csr[eB]; wB = wb1[(size_t)eB * 4 + hh];
        uB = *(const uint4*)&Fb[(size_t)s * 128 + l * 8];
    }

    for (int e = eA; e < e1; e += 8) {
        int nA = e + 8, nB = e + 12;
        float wA2 = 0.f, wB2 = 0.f;
        uint4 uA2 = {0u,0u,0u,0u}, uB2 = {0u,0u,0u,0u};
        if (nA < e1) {
            int s = csr[nA]; wA2 = wb1[(size_t)nA * 4 + hh];
            uA2 = *(const uint4*)&Fb[(size_t)s * 128 + l * 8];
        }
        if (nB < e1) {
            int s = csr[nB]; wB2 = wb1[(size_t)nB * 4 + hh];
            uB2 = *(const uint4*)&Fb[(size_t)s * 128 + l * 8];
        }
        a0 = fmaf(wA, bflo(uA.x), a0); a1 = fmaf(wA, bfhi(uA.x), a1);
        a2 = fmaf(wA, bflo(uA.y), a2); a3 = fmaf(wA, bfhi(uA.y), a3);
        a4 = fmaf(wA, bflo(uA.z), a4); a5 = fmaf(wA, bfhi(uA.z), a5);
        a6 = fmaf(wA, bflo(uA.w), a6); a7 = fmaf(wA, bfhi(uA.w), a7);
        a0 = fmaf(wB, bflo(uB.x), a0); a1 = fmaf(wB, bfhi(uB.x), a1);
        a2 = fmaf(wB, bflo(uB.y), a2); a3 = fmaf(wB, bfhi(uB.y), a3);
        a4 = fmaf(wB, bflo(uB.z), a4); a5 = fmaf(wB, bfhi(uB.z), a5);
        a6 = fmaf(wB, bflo(uB.w), a6); a7 = fmaf(wB, bfhi(uB.w), a7);
        dsum += wA + wB;
        uA = uA2; uB = uB2; wA = wA2; wB = wB2;
    }

    #pragma unroll
    for (int m = 16; m <= 32; m <<= 1) {
        a0 += __shfl_xor(a0, m, 64); a1 += __shfl_xor(a1, m, 64);
        a2 += __shfl_xor(a2, m, 64); a3 += __shfl_xor(a3, m, 64);
        a4 += __shfl_xor(a4, m, 64); a5 += __shfl_xor(a5, m, 64);
        a6 += __shfl_xor(a6, m, 64); a7 += __shfl_xor(a7, m, 64);
        dsum += __shfl_xor(dsum, m, 64);
    }

    float inv = 1.f / (dsum + EPS_DEN);
    float o[8] = {a0, a1, a2, a3, a4, a5, a6, a7};
    #pragma unroll
    for (int j = 0; j < 8; ++j) {
        float v = fmaf(o[j], inv, b1[l * 8 + j]);
        o[j] = v > 0.f ? v : __expf(v) - 1.f;
    }
    if (g == 0) {
        *(float4*)&h1row[wid][l * 8]     = make_float4(o[0], o[1], o[2], o[3]);
        *(float4*)&h1row[wid][l * 8 + 4] = make_float4(o[4], o[5], o[6], o[7]);
    }
    // wave-coherent LDS RAW within the same wave

    int j = t & 31, halfk = t >> 5;
    float part = 0.f;
    int kb = halfk << 6;
    #pragma unroll 8
    for (int k = 0; k < 64; ++k)
        part = fmaf(h1row[wid][kb + k], W2[(size_t)(kb + k) * 32 + j], part);
    part += __shfl_xor(part, 32, 64);

    if (t < 32) {
        feat2b[(size_t)n * 32 + j] = f2bf(part);
        float sl = part * al2[j];
        float sr = part * ar2[j];
        #pragma unroll
        for (int m = 16; m >= 1; m >>= 1) {
            sl += __shfl_xor(sl, m, 64);
            sr += __shfl_xor(sr, m, 64);
        }
        if (j == 0) { el2[n] = sl; er2[n] = sr; }
    }
}

// ---------------- layer-2 edge weights ----------------

__global__ void w2_k(const int* __restrict__ src, const int* __restrict__ dst,
                     const int* __restrict__ perm, const float* __restrict__ el2,
                     const float* __restrict__ er2, float* __restrict__ w2buf) {
    int e = blockIdx.x * 256 + threadIdx.x;
    if (e >= N_EDGES) return;
    float x = el2[src[e]] + er2[dst[e]];
    x = x > 0.f ? x : NEG_SLOPE * x;
    w2buf[perm[e]] = __expf(x);
}

// ---------------- agg2: wave-per-node, 16 edge slots x 4 lanes (bf16x8) ----------------

__global__ __launch_bounds__(256) void agg2_k(const unsigned short* __restrict__ F2b,
                                              const int* __restrict__ off,
                                              const int* __restrict__ csr,
                                              const float* __restrict__ w2,
                                              const float* __restrict__ b2,
                                              float* __restrict__ out) {
    int wid = threadIdx.x >> 6;
    int n = blockIdx.x * 4 + wid;
    if (n >= N_NODES) return;
    int t = threadIdx.x & 63;
    int g = t >> 2, l = t & 3;   // dims 8l..8l+7
    int e0 = off[n], e1 = off[n + 1];

    float a0 = 0.f, a1 = 0.f, a2 = 0.f, a3 = 0.f, a4 = 0.f, a5 = 0.f, a6 = 0.f, a7 = 0.f;
    float dsum = 0.f;
    for (int e = e0 + g; e < e1; e += 16) {
        int s = csr[e];
        float w = w2[e];
        uint4 u = *(const uint4*)&F2b[(size_t)s * 32 + l * 8];
        a0 = fmaf(w, bflo(u.x), a0); a1 = fmaf(w, bfhi(u.x), a1);
        a2 = fmaf(w, bflo(u.y), a2); a3 = fmaf(w, bfhi(u.y), a3);
        a4 = fmaf(w, bflo(u.z), a4); a5 = fmaf(w, bfhi(u.z), a5);
        a6 = fmaf(w, bflo(u.w), a6); a7 = fmaf(w, bfhi(u.w), a7);
        dsum += w;
    }
    #pragma unroll
    for (int m = 4; m <= 32; m <<= 1) {
        a0 += __shfl_xor(a0, m, 64); a1 += __shfl_xor(a1, m, 64);
        a2 += __shfl_xor(a2, m, 64); a3 += __shfl_xor(a3, m, 64);
        a4 += __shfl_xor(a4, m, 64); a5 += __shfl_xor(a5, m, 64);
        a6 += __shfl_xor(a6, m, 64); a7 += __shfl_xor(a7, m, 64);
        dsum += __shfl_xor(dsum, m, 64);
    }
    if (t < 4) {
        float inv = 1.f / (dsum + EPS_DEN);
        float4 r0, r1;
        r0.x = fmaf(a0, inv, b2[l * 8 + 0]);
        r0.y = fmaf(a1, inv, b2[l * 8 + 1]);
        r0.z = fmaf(a2, inv, b2[l * 8 + 2]);
        r0.w = fmaf(a3, inv, b2[l * 8 + 3]);
        r1.x = fmaf(a4, inv, b2[l * 8 + 4]);
        r1.y = fmaf(a5, inv, b2[l * 8 + 5]);
        r1.z = fmaf(a6, inv, b2[l * 8 + 6]);
        r1.w = fmaf(a7, inv, b2[l * 8 + 7]);
        *(float4*)&out[(size_t)n * 32 + l * 8]     = r0;
        *(float4*)&out[(size_t)n * 32 + l * 8 + 4] = r1;
    }
}

// ---------------- launch ----------------

extern "C" void kernel_launch(void* const* d_in, const int* in_sizes, int n_in,
                              void* d_out, int out_size, void* d_ws, size_t ws_size,
                              hipStream_t stream) {
    const float* h   = (const float*)d_in[0];
    const float* W1  = (const float*)d_in[1];
    const float* al1 = (const float*)d_in[2];
    const float* ar1 = (const float*)d_in[3];
    const float* b1  = (const float*)d_in[4];
    const float* W2  = (const float*)d_in[5];
    const float* al2 = (const float*)d_in[6];
    const float* ar2 = (const float*)d_in[7];
    const float* b2  = (const float*)d_in[8];
    const int* src   = (const int*)d_in[9];
    const int* dst   = (const int*)d_in[10];
    float* out = (float*)d_out;

    char* wsb = (char*)d_ws;
    size_t o = 0;
    auto alloc = [&](size_t bytes) {
        void* p = wsb + o;
        o += (bytes + 255) & ~(size_t)255;
        return p;
    };
    int* deg     = (int*)alloc((size_t)N_NODES * 4);
    int* off     = (int*)alloc((size_t)(N_NODES + 1) * 4);
    int* cursor  = (int*)alloc((size_t)N_NODES * 4);
    int* csr     = (int*)alloc((size_t)N_EDGES * 4);
    int* perm    = (int*)alloc((size_t)N_EDGES * 4);
    int* bsum    = (int*)alloc((size_t)NB_SCAN * 4);
    unsigned short* Wt     = (unsigned short*)alloc((size_t)128 * 256 * 2);
    unsigned short* feat1b = (unsigned short*)alloc((size_t)N_NODES * 128 * 2);
    float* el1   = (float*)alloc((size_t)N_NODES * 4 * 4);
    float* er1   = (float*)alloc((size_t)N_NODES * 4 * 4);
    float* wb1   = (float*)alloc((size_t)N_EDGES * 4 * 4);
    unsigned short* feat2b = (unsigned short*)alloc((size_t)N_NODES * 32 * 2);
    float* el2   = (float*)alloc((size_t)N_NODES * 4);
    float* er2   = (float*)alloc((size_t)N_NODES * 4);
    float* w2buf = wb1;  // reuse: wb1 dead after agg1

    hipMemsetAsync(deg, 0, (size_t)N_NODES * 4, stream);
    prep_k<<<(128 * 256 + 255) / 256, 256, 0, stream>>>(W1, Wt);
    count_k<<<(N_EDGES + 255) / 256, 256, 0, stream>>>(dst, deg);
    scan1_k<<<NB_SCAN, 256, 0, stream>>>(deg, off, bsum);
    scan3_k<<<(N_NODES + 255) / 256, 256, 0, stream>>>(off, bsum);
    hipMemcpyAsync(cursor, off, (size_t)N_NODES * 4, hipMemcpyDeviceToDevice, stream);
    gemm1_k<<<(N_NODES + 127) / 128, 256, 0, stream>>>(h, Wt, feat1b);
    elr1_k<<<(N_NODES * 4 + 255) / 256, 256, 0, stream>>>(feat1b, al1, ar1, el1, er1);
    scatter_k<<<(N_EDGES + 255) / 256, 256, 0, stream>>>(src, dst, cursor, csr, perm,
                                                         el1, er1, wb1);
    agg1_k<<<(N_NODES + 3) / 4, 256, 0, stream>>>(feat1b, off, csr, wb1, b1, W2,
                                                  al2, ar2, feat2b, el2, er2);
    w2_k<<<(N_EDGES + 255) / 256, 256, 0, stream>>>(src, dst, perm, el2, er2, w2buf);
    agg2_k<<<(N_NODES + 3) / 4, 256, 0, stream>>>(feat2b, off, csr, w2buf, b2, out);
}

// Round 8
// 221.368 us; speedup vs baseline: 1.2662x; 1.0498x over previous
//
#include <hip/hip_runtime.h>
#include <hip/hip_bf16.h>
#include <math.h>

#define N_NODES 50000
#define N_EDGES 800000
#define NEG_SLOPE 0.2f
#define EPS_DEN 1e-9f

constexpr int SCAN_BLK = 1024;
constexpr int NB_SCAN = (N_NODES + SCAN_BLK - 1) / SCAN_BLK; // 49

typedef __attribute__((ext_vector_type(8))) short short8v;
typedef __attribute__((ext_vector_type(4))) float f32x4;

__device__ inline unsigned short f2bf(float x) {
    __hip_bfloat16 h = __float2bfloat16(x);
    return *(unsigned short*)&h;
}
__device__ inline float bflo(unsigned int u) { return __uint_as_float(u << 16); }
__device__ inline float bfhi(unsigned int u) { return __uint_as_float(u & 0xffff0000u); }
__device__ inline float leaky(float x) { return x > 0.f ? x : NEG_SLOPE * x; }

// ---------------- CSR build ----------------

__global__ void count_k(const int* __restrict__ dst, int* __restrict__ deg) {
    int e = blockIdx.x * 256 + threadIdx.x;
    if (e < N_EDGES) atomicAdd(&deg[dst[e]], 1);
}

__global__ void scan1_k(const int* __restrict__ deg, int* __restrict__ off,
                        int* __restrict__ bsum) {
    __shared__ int sh[256];
    int b = blockIdx.x, t = threadIdx.x;
    int base = b * SCAN_BLK + t * 4;
    int v[4]; int s = 0;
    #pragma unroll
    for (int i = 0; i < 4; ++i) {
        int idx = base + i;
        v[i] = (idx < N_NODES) ? deg[idx] : 0;
        s += v[i];
    }
    sh[t] = s; __syncthreads();
    for (int ofs = 1; ofs < 256; ofs <<= 1) {
        int x = 0;
        if (t >= ofs) x = sh[t - ofs];
        __syncthreads();
        sh[t] += x;
        __syncthreads();
    }
    int excl = sh[t] - s;
    if (t == 255) bsum[b] = sh[255];
    int run = excl;
    #pragma unroll
    for (int i = 0; i < 4; ++i) {
        int idx = base + i;
        if (idx < N_NODES) off[idx] = run;
        run += v[i];
    }
}

// merged scan2+scan3
__global__ void scan3_k(int* __restrict__ off, const int* __restrict__ bsum) {
    __shared__ int pre;
    int b = blockIdx.x;
    if (threadIdx.x == 0) {
        int s = 0;
        int nb = b >> 2;
        for (int j = 0; j < nb; ++j) s += bsum[j];
        pre = s;
    }
    __syncthreads();
    int i = b * 256 + threadIdx.x;
    if (i < N_NODES) off[i] += pre;
    if (i == 0) off[N_NODES] = N_EDGES;
}

// bare CSR scatter
__global__ void scatter_k(const int* __restrict__ src, const int* __restrict__ dst,
                          int* __restrict__ cursor, int* __restrict__ csr) {
    int e = blockIdx.x * 256 + threadIdx.x;
    if (e >= N_EDGES) return;
    int p = atomicAdd(&cursor[dst[e]], 1);
    csr[p] = src[e];
}

// ---------------- prep: Wt[col][k] = bf16(W1[k][col]) ----------------

__global__ void prep_k(const float* __restrict__ W, unsigned short* __restrict__ Wt) {
    int i = blockIdx.x * 256 + threadIdx.x;   // i = col*256 + k
    if (i >= 128 * 256) return;
    int col = i >> 8, k = i & 255;
    Wt[i] = f2bf(W[(size_t)k * 128 + col]);
}

// ---------------- GEMM1 (MFMA, zero-LDS): feat1b = bf16(H @ W1) ----------------

__global__ __launch_bounds__(256) void gemm1_k(const float* __restrict__ H,
                                               const unsigned short* __restrict__ Wt,
                                               unsigned short* __restrict__ Fb) {
    int t = threadIdx.x;
    int w = t >> 6, l = t & 63;
    int lr = l & 15, lk = l >> 4;
    int rowBase = blockIdx.x * 128 + w * 32;
    f32x4 acc[2][8] = {};

    #pragma unroll 2
    for (int kc = 0; kc < 8; ++kc) {
        int k0 = kc * 32 + lk * 8;
        short8v ah[2], alo[2];
        #pragma unroll
        for (int rf = 0; rf < 2; ++rf) {
            int row = rowBase + rf * 16 + lr;
            float hv[8];
            if (row < N_NODES) {
                float4 x0 = *(const float4*)&H[(size_t)row * 256 + k0];
                float4 x1 = *(const float4*)&H[(size_t)row * 256 + k0 + 4];
                hv[0] = x0.x; hv[1] = x0.y; hv[2] = x0.z; hv[3] = x0.w;
                hv[4] = x1.x; hv[5] = x1.y; hv[6] = x1.z; hv[7] = x1.w;
            } else {
                #pragma unroll
                for (int i = 0; i < 8; ++i) hv[i] = 0.f;
            }
            #pragma unroll
            for (int i = 0; i < 8; ++i) {
                unsigned short hi = f2bf(hv[i]);
                float hif = __uint_as_float((unsigned)hi << 16);
                ah[rf][i]  = (short)hi;
                alo[rf][i] = (short)f2bf(hv[i] - hif);
            }
        }
        #pragma unroll
        for (int cf = 0; cf < 8; ++cf) {
            short8v b = *(const short8v*)&Wt[(size_t)(cf * 16 + lr) * 256 + k0];
            acc[0][cf] = __builtin_amdgcn_mfma_f32_16x16x32_bf16(ah[0],  b, acc[0][cf], 0, 0, 0);
            acc[0][cf] = __builtin_amdgcn_mfma_f32_16x16x32_bf16(alo[0], b, acc[0][cf], 0, 0, 0);
            acc[1][cf] = __builtin_amdgcn_mfma_f32_16x16x32_bf16(ah[1],  b, acc[1][cf], 0, 0, 0);
            acc[1][cf] = __builtin_amdgcn_mfma_f32_16x16x32_bf16(alo[1], b, acc[1][cf], 0, 0, 0);
        }
    }

    #pragma unroll
    for (int rf = 0; rf < 2; ++rf) {
        #pragma unroll
        for (int r = 0; r < 4; ++r) {
            int row = rowBase + rf * 16 + lk * 4 + r;
            if (row < N_NODES) {
                #pragma unroll
                for (int cf = 0; cf < 8; ++cf)
                    Fb[(size_t)row * 128 + cf * 16 + lr] = f2bf(acc[rf][cf][r]);
            }
        }
    }
}

// ---------------- el1/er1 from bf16 feat1 ----------------

__global__ void elr1_k(const unsigned short* __restrict__ Fb,
                       const float* __restrict__ al, const float* __restrict__ ar,
                       float* __restrict__ el, float* __restrict__ er) {
    int i = blockIdx.x * 256 + threadIdx.x;
    if (i >= N_NODES * 4) return;
    int hh = i & 3;
    const unsigned short* f = &Fb[(size_t)(i >> 2) * 128 + hh * 32];
    float sl = 0.f, sr = 0.f;
    #pragma unroll
    for (int q = 0; q < 4; ++q) {
        uint4 u = *(const uint4*)&f[q * 8];
        const float* A = &al[hh * 32 + q * 8];
        const float* B = &ar[hh * 32 + q * 8];
        float v0 = bflo(u.x), v1 = bfhi(u.x), v2 = bflo(u.y), v3 = bfhi(u.y);
        float v4 = bflo(u.z), v5 = bfhi(u.z), v6 = bflo(u.w), v7 = bfhi(u.w);
        sl += v0*A[0] + v1*A[1] + v2*A[2] + v3*A[3] + v4*A[4] + v5*A[5] + v6*A[6] + v7*A[7];
        sr += v0*B[0] + v1*B[1] + v2*B[2] + v3*B[3] + v4*B[4] + v5*B[5] + v6*B[6] + v7*B[7];
    }
    el[i] = sl; er[i] = sr;
}

// ---------------- agg1: wave-per-node, pair-pipelined gathers, inline weights ----------------
// wave lanes: g = slot 0..3, l = dim group 0..15 (dims 8l..8l+7), head l>>2.

__global__ __launch_bounds__(256) void agg1_k(const unsigned short* __restrict__ Fb,
                                              const int* __restrict__ off,
                                              const int* __restrict__ csr,
                                              const float* __restrict__ el1,
                                              const float* __restrict__ er1,
                                              const float* __restrict__ b1,
                                              const float* __restrict__ W2,
                                              const float* __restrict__ al2,
                                              const float* __restrict__ ar2,
                                              unsigned short* __restrict__ feat2b,
                                              float* __restrict__ el2,
                                              float* __restrict__ er2) {
    __shared__ float h1row[4][128];
    int wid = threadIdx.x >> 6;
    int n = blockIdx.x * 4 + wid;
    if (n >= N_NODES) return;
    int t = threadIdx.x & 63;
    int g = t >> 4;
    int l = t & 15;
    int hh = l >> 2;
    int e0 = off[n], e1 = off[n + 1];
    float ern = er1[(size_t)n * 4 + hh];

    float a0 = 0.f, a1 = 0.f, a2 = 0.f, a3 = 0.f, a4 = 0.f, a5 = 0.f, a6 = 0.f, a7 = 0.f;
    float dsum = 0.f;

    int eA = e0 + g, eB = eA + 4;
    float xA = -INFINITY, xB = -INFINITY;
    uint4 uA = {0u,0u,0u,0u}, uB = {0u,0u,0u,0u};
    if (eA < e1) {
        int s = csr[eA]; xA = el1[(size_t)s * 4 + hh];
        uA = *(const uint4*)&Fb[(size_t)s * 128 + l * 8];
    }
    if (eB < e1) {
        int s = csr[eB]; xB = el1[(size_t)s * 4 + hh];
        uB = *(const uint4*)&Fb[(size_t)s * 128 + l * 8];
    }

    for (int e = eA; e < e1; e += 8) {
        int nA = e + 8, nB = e + 12;
        float xA2 = -INFINITY, xB2 = -INFINITY;
        uint4 uA2 = {0u,0u,0u,0u}, uB2 = {0u,0u,0u,0u};
        if (nA < e1) {
            int s = csr[nA]; xA2 = el1[(size_t)s * 4 + hh];
            uA2 = *(const uint4*)&Fb[(size_t)s * 128 + l * 8];
        }
        if (nB < e1) {
            int s = csr[nB]; xB2 = el1[(size_t)s * 4 + hh];
            uB2 = *(const uint4*)&Fb[(size_t)s * 128 + l * 8];
        }
        float wA = __expf(leaky(xA + ern));
        float wB = __expf(leaky(xB + ern));
        a0 = fmaf(wA, bflo(uA.x), a0); a1 = fmaf(wA, bfhi(uA.x), a1);
        a2 = fmaf(wA, bflo(uA.y), a2); a3 = fmaf(wA, bfhi(uA.y), a3);
        a4 = fmaf(wA, bflo(uA.z), a4); a5 = fmaf(wA, bfhi(uA.z), a5);
        a6 = fmaf(wA, bflo(uA.w), a6); a7 = fmaf(wA, bfhi(uA.w), a7);
        a0 = fmaf(wB, bflo(uB.x), a0); a1 = fmaf(wB, bfhi(uB.x), a1);
        a2 = fmaf(wB, bflo(uB.y), a2); a3 = fmaf(wB, bfhi(uB.y), a3);
        a4 = fmaf(wB, bflo(uB.z), a4); a5 = fmaf(wB, bfhi(uB.z), a5);
        a6 = fmaf(wB, bflo(uB.w), a6); a7 = fmaf(wB, bfhi(uB.w), a7);
        dsum += wA + wB;
        uA = uA2; uB = uB2; xA = xA2; xB = xB2;
    }

    #pragma unroll
    for (int m = 16; m <= 32; m <<= 1) {
        a0 += __shfl_xor(a0, m, 64); a1 += __shfl_xor(a1, m, 64);
        a2 += __shfl_xor(a2, m, 64); a3 += __shfl_xor(a3, m, 64);
        a4 += __shfl_xor(a4, m, 64); a5 += __shfl_xor(a5, m, 64);
        a6 += __shfl_xor(a6, m, 64); a7 += __shfl_xor(a7, m, 64);
        dsum += __shfl_xor(dsum, m, 64);
    }

    float inv = 1.f / (dsum + EPS_DEN);
    float o[8] = {a0, a1, a2, a3, a4, a5, a6, a7};
    #pragma unroll
    for (int j = 0; j < 8; ++j) {
        float v = fmaf(o[j], inv, b1[l * 8 + j]);
        o[j] = v > 0.f ? v : __expf(v) - 1.f;
    }
    if (g == 0) {
        *(float4*)&h1row[wid][l * 8]     = make_float4(o[0], o[1], o[2], o[3]);
        *(float4*)&h1row[wid][l * 8 + 4] = make_float4(o[4], o[5], o[6], o[7]);
    }
    // wave-coherent LDS RAW within the same wave

    // fused GEMM2, j-quad form: lane = 4 cols (jq) x 16 k's (kb2)
    int jq = (t & 7) * 4;
    int kb2 = (t >> 3) * 16;
    float p0 = 0.f, p1 = 0.f, p2 = 0.f, p3 = 0.f;
    #pragma unroll
    for (int k = 0; k < 16; ++k) {
        float hv = h1row[wid][kb2 + k];
        float4 wv = *(const float4*)&W2[(size_t)(kb2 + k) * 32 + jq];
        p0 = fmaf(hv, wv.x, p0);
        p1 = fmaf(hv, wv.y, p1);
        p2 = fmaf(hv, wv.z, p2);
        p3 = fmaf(hv, wv.w, p3);
    }
    #pragma unroll
    for (int m = 8; m <= 32; m <<= 1) {
        p0 += __shfl_xor(p0, m, 64);
        p1 += __shfl_xor(p1, m, 64);
        p2 += __shfl_xor(p2, m, 64);
        p3 += __shfl_xor(p3, m, 64);
    }
    if (t < 8) {
        ushort4 fv = {f2bf(p0), f2bf(p1), f2bf(p2), f2bf(p3)};
        *(ushort4*)&feat2b[(size_t)n * 32 + jq] = fv;
        float sl = p0 * al2[jq] + p1 * al2[jq + 1] + p2 * al2[jq + 2] + p3 * al2[jq + 3];
        float sr = p0 * ar2[jq] + p1 * ar2[jq + 1] + p2 * ar2[jq + 2] + p3 * ar2[jq + 3];
        #pragma unroll
        for (int m = 1; m <= 4; m <<= 1) {
            sl += __shfl_xor(sl, m, 64);
            sr += __shfl_xor(sr, m, 64);
        }
        if (t == 0) { el2[n] = sl; er2[n] = sr; }
    }
}

// ---------------- agg2: wave-per-node, inline weights ----------------

__global__ __launch_bounds__(256) void agg2_k(const unsigned short* __restrict__ F2b,
                                              const int* __restrict__ off,
                                              const int* __restrict__ csr,
                                              const float* __restrict__ el2,
                                              const float* __restrict__ er2,
                                              const float* __restrict__ b2,
                                              float* __restrict__ out) {
    int wid = threadIdx.x >> 6;
    int n = blockIdx.x * 4 + wid;
    if (n >= N_NODES) return;
    int t = threadIdx.x & 63;
    int g = t >> 2, l = t & 3;   // dims 8l..8l+7
    int e0 = off[n], e1 = off[n + 1];
    float ern = er2[n];

    float a0 = 0.f, a1 = 0.f, a2 = 0.f, a3 = 0.f, a4 = 0.f, a5 = 0.f, a6 = 0.f, a7 = 0.f;
    float dsum = 0.f;
    for (int e = e0 + g; e < e1; e += 16) {
        int s = csr[e];
        float w = __expf(leaky(el2[s] + ern));
        uint4 u = *(const uint4*)&F2b[(size_t)s * 32 + l * 8];
        a0 = fmaf(w, bflo(u.x), a0); a1 = fmaf(w, bfhi(u.x), a1);
        a2 = fmaf(w, bflo(u.y), a2); a3 = fmaf(w, bfhi(u.y), a3);
        a4 = fmaf(w, bflo(u.z), a4); a5 = fmaf(w, bfhi(u.z), a5);
        a6 = fmaf(w, bflo(u.w), a6); a7 = fmaf(w, bfhi(u.w), a7);
        dsum += w;
    }
    #pragma unroll
    for (int m = 4; m <= 32; m <<= 1) {
        a0 += __shfl_xor(a0, m, 64); a1 += __shfl_xor(a1, m, 64);
        a2 += __shfl_xor(a2, m, 64); a3 += __shfl_xor(a3, m, 64);
        a4 += __shfl_xor(a4, m, 64); a5 += __shfl_xor(a5, m, 64);
        a6 += __shfl_xor(a6, m, 64); a7 += __shfl_xor(a7, m, 64);
        dsum += __shfl_xor(dsum, m, 64);
    }
    if (t < 4) {
        float inv = 1.f / (dsum + EPS_DEN);
        float4 r0, r1;
        r0.x = fmaf(a0, inv, b2[l * 8 + 0]);
        r0.y = fmaf(a1, inv, b2[l * 8 + 1]);
        r0.z = fmaf(a2, inv, b2[l * 8 + 2]);
        r0.w = fmaf(a3, inv, b2[l * 8 + 3]);
        r1.x = fmaf(a4, inv, b2[l * 8 + 4]);
        r1.y = fmaf(a5, inv, b2[l * 8 + 5]);
        r1.z = fmaf(a6, inv, b2[l * 8 + 6]);
        r1.w = fmaf(a7, inv, b2[l * 8 + 7]);
        *(float4*)&out[(size_t)n * 32 + l * 8]     = r0;
        *(float4*)&out[(size_t)n * 32 + l * 8 + 4] = r1;
    }
}

// ---------------- launch ----------------

extern "C" void kernel_launch(void* const* d_in, const int* in_sizes, int n_in,
                              void* d_out, int out_size, void* d_ws, size_t ws_size,
                              hipStream_t stream) {
    const float* h   = (const float*)d_in[0];
    const float* W1  = (const float*)d_in[1];
    const float* al1 = (const float*)d_in[2];
    const float* ar1 = (const float*)d_in[3];
    const float* b1  = (const float*)d_in[4];
    const float* W2  = (const float*)d_in[5];
    const float* al2 = (const float*)d_in[6];
    const float* ar2 = (const float*)d_in[7];
    const float* b2  = (const float*)d_in[8];
    const int* src   = (const int*)d_in[9];
    const int* dst   = (const int*)d_in[10];
    float* out = (float*)d_out;

    char* wsb = (char*)d_ws;
    size_t o = 0;
    auto alloc = [&](size_t bytes) {
        void* p = wsb + o;
        o += (bytes + 255) & ~(size_t)255;
        return p;
    };
    int* deg     = (int*)alloc((size_t)N_NODES * 4);
    int* off     = (int*)alloc((size_t)(N_NODES + 1) * 4);
    int* cursor  = (int*)alloc((size_t)N_NODES * 4);
    int* csr     = (int*)alloc((size_t)N_EDGES * 4);
    int* bsum    = (int*)alloc((size_t)NB_SCAN * 4);
    unsigned short* Wt     = (unsigned short*)alloc((size_t)128 * 256 * 2);
    unsigned short* feat1b = (unsigned short*)alloc((size_t)N_NODES * 128 * 2);
    float* el1   = (float*)alloc((size_t)N_NODES * 4 * 4);
    float* er1   = (float*)alloc((size_t)N_NODES * 4 * 4);
    unsigned short* feat2b = (unsigned short*)alloc((size_t)N_NODES * 32 * 2);
    float* el2   = (float*)alloc((size_t)N_NODES * 4);
    float* er2   = (float*)alloc((size_t)N_NODES * 4);

    hipMemsetAsync(deg, 0, (size_t)N_NODES * 4, stream);
    count_k<<<(N_EDGES + 255) / 256, 256, 0, stream>>>(dst, deg);
    scan1_k<<<NB_SCAN, 256, 0, stream>>>(deg, off, bsum);
    scan3_k<<<(N_NODES + 255) / 256, 256, 0, stream>>>(off, bsum);
    hipMemcpyAsync(cursor, off, (size_t)N_NODES * 4, hipMemcpyDeviceToDevice, stream);
    scatter_k<<<(N_EDGES + 255) / 256, 256, 0, stream>>>(src, dst, cursor, csr);
    prep_k<<<(128 * 256 + 255) / 256, 256, 0, stream>>>(W1, Wt);
    gemm1_k<<<(N_NODES + 127) / 128, 256, 0, stream>>>(h, Wt, feat1b);
    elr1_k<<<(N_NODES * 4 + 255) / 256, 256, 0, stream>>>(feat1b, al1, ar1, el1, er1);
    agg1_k<<<(N_NODES + 3) / 4, 256, 0, stream>>>(feat1b, off, csr, el1, er1, b1, W2,
                                                  al2, ar2, feat2b, el2, er2);
    agg2_k<<<(N_NODES + 3) / 4, 256, 0, stream>>>(feat2b, off, csr, el2, er2, b2, out);
}